// Round 8
// baseline (352.018 us; speedup 1.0000x reference)
//
#include <hip/hip_runtime.h>

// MoE fused forward: out = (relu(x@W1[e]+b1[e])@W2[e]+b2[e]) * exp(min(T, log100))
// N=524288, D=128, H=512, E=8, contiguous expert chunks.
// R8: R6's producer/consumer wave specialization (512 blocks x 1024 thr), with
// PAIR-CHUNK intervals on a 4-deep hsb ring: interval i produces chunks
// 2i,2i+1 -> bufs {A,B}/{C,D} while consumers drain the previous pair.
// Barriers/tile 11 -> 7; buffer reuse is >=2 barriers apart (race-free with
// lgkm-only barriers). LDS = w1s 128K + ring 32K = 160 KiB exactly (xs aliases
// bufs C,D; b1 bias moved to producer regs). s_setprio around MFMA clusters
// (T5: role-split schedule). All layouts identical to R6 (absmax 0.03125).

#define CLAMP_MAXV 4.605170185988091f

typedef __attribute__((ext_vector_type(8))) short s16x8;
typedef __attribute__((ext_vector_type(4))) float f32x4;
typedef __attribute__((ext_vector_type(4))) unsigned short u16x4;
typedef __attribute__((ext_vector_type(8))) unsigned short u16x8;

static __device__ __forceinline__ unsigned short f2bf(float f) {
  union { float f; unsigned int u; } v; v.f = f;
  unsigned int r = v.u + 0x7FFFu + ((v.u >> 16) & 1u);  // RNE
  return (unsigned short)(r >> 16);
}

static __device__ __forceinline__ void gll16(const void* src, void* dst) {
  __builtin_amdgcn_global_load_lds((const __attribute__((address_space(1))) void*)src,
                                   (__attribute__((address_space(3))) void*)dst, 16, 0, 0);
}

// LDS-only barrier: own-wave lgkm drain + s_barrier (vmcnt NOT drained; the only
// in-flight VMEM are reg-prefetch loads, waited by compiler before use).
#define LBAR() do { \
  asm volatile("s_waitcnt lgkmcnt(0)" ::: "memory"); \
  __builtin_amdgcn_s_barrier(); \
  __builtin_amdgcn_sched_barrier(0); \
} while (0)

// ---- pre-kernel: W1[e][d][h] -> w1t[e][h][d] bf16 ; W2[e][h][d] -> w2t[e][d][h] bf16
__global__ void conv_w(const float* __restrict__ W1, const float* __restrict__ W2,
                       unsigned short* __restrict__ w1t, unsigned short* __restrict__ w2t) {
  int idx = blockIdx.x * 256 + threadIdx.x;  // 131072 total
  if (idx < 65536) {
    int h  = idx & 511;
    int d0 = ((idx >> 9) & 15) << 3;
    int e  = idx >> 13;
    const float* src = W1 + ((size_t)e << 16);
    u16x8 v;
#pragma unroll
    for (int j = 0; j < 8; ++j) v[j] = f2bf(src[(size_t)(d0 + j) * 512 + h]);
    *(u16x8*)(w1t + ((((size_t)e << 9) + h) << 7) + d0) = v;
  } else {
    int i2 = idx - 65536;
    int d  = i2 & 127;
    int h0 = ((i2 >> 7) & 63) << 3;
    int e  = i2 >> 13;
    const float* src = W2 + ((size_t)e << 16);
    u16x8 v;
#pragma unroll
    for (int j = 0; j < 8; ++j) v[j] = f2bf(src[(size_t)(h0 + j) * 128 + d]);
    *(u16x8*)(w2t + ((((size_t)e << 7) + d) << 9) + h0) = v;
  }
}

// ---- fused MoE kernel (wave-specialized, pair-chunk intervals)
__global__ __launch_bounds__(1024, 4) void moe_fused(
    const float* __restrict__ x,
    const float* __restrict__ b1,
    const float* __restrict__ b2,
    const float* __restrict__ temp,
    const unsigned short* __restrict__ w1t,
    const unsigned short* __restrict__ w2t,
    float* __restrict__ out)
{
  __shared__ __align__(16) char smem[163840];
  char* const w1s = smem;             // 128 KB [512 h][128 d] bf16, swz ^((h&7)<<4)
  char* const hb0 = smem + 131072;    // 8 KB rings: [64 tok][64 h] bf16, swz ^((tok&7)<<4)
  char* const hb1 = smem + 139264;
  char* const hb2 = smem + 147456;
  char* const hb3 = smem + 155648;
  char* const xs  = smem + 147456;    // 16 KB [64 tok][128 d] bf16 (aliases hb2+hb3)

  const int tid  = threadIdx.x;
  const int lane = tid & 63;
  const int wid  = tid >> 6;          // 0..15
  const int l15  = lane & 15;
  const int lg   = lane >> 4;
  const int blk  = blockIdx.x;
  const int e    = blk >> 6;          // 64 blocks per expert
  const size_t tok0 = (size_t)blk << 10;   // 1024 tokens per block

  const unsigned short* w1g = w1t + ((size_t)e << 16);
  const unsigned short* w2g = w2t + ((size_t)e << 16);
  const float* xblk = x + (tok0 << 7);
  float* const oblk = out + (tok0 << 7);

  // ---- prologue: stage w1 (128 KB) once per block, source pre-swizzled
#pragma unroll
  for (int k = 0; k < 8; ++k) {
    int s = tid + (k << 10);          // 0..8191 slots of 16 B
    int h = s >> 4, sr = s & 15;
    gll16(w1g + ((size_t)h << 7) + ((sr ^ (h & 7)) << 3), w1s + (s << 4));
  }

  // x tile 0 into regs (each thread owns 8 floats)
  f32x4 xv[2];
  xv[0] = *(const f32x4*)(xblk + (tid << 3));
  xv[1] = *(const f32x4*)(xblk + (tid << 3) + 4);

  __syncthreads();  // full drain: w1s landed

  // xs-write address: tok = tid>>4, col = (tid&15)*8
  const int xtok = tid >> 4;
  const unsigned xaddr = (unsigned)((xtok << 8) + ((tid & 15) << 4)) ^ (unsigned)((xtok & 7) << 4);

  if (wid < 8) {
    // ================= PRODUCER: GEMM1 =================
    const int hr  = wid & 3;
    const int tq0 = (wid >> 2) << 5;
    const unsigned hl2 = (unsigned)(((hr << 4) + (lg << 2)) << 1);
    char* const hbuf[4] = {hb0, hb1, hb2, hb3};

    // bias regs: 8 chunks x 4 consecutive h (statically indexed, loaded once)
    f32x4 bias[8];
    const float* b1e = b1 + (e << 9);
#pragma unroll
    for (int c = 0; c < 8; ++c)
      bias[c] = *(const f32x4*)(b1e + (c << 6) + (hr << 4) + (lg << 2));

#pragma unroll 1
    for (int t = 0; t < 16; ++t) {
      // write xs
      u16x8 p;
#pragma unroll
      for (int i = 0; i < 8; ++i) p[i] = f2bf(xv[i >> 2][i & 3]);
      *(u16x8*)(xs + xaddr) = p;
      LBAR();

      // hoist x fragments (wave's 32-token half)
      s16x8 xb[2][4];
#pragma unroll
      for (int j = 0; j < 2; ++j) {
        int tk = tq0 + (j << 4) + l15;
#pragma unroll
        for (int ks = 0; ks < 4; ++ks) {
          unsigned koff = (unsigned)((ks << 6) + (lg << 4));
          xb[j][ks] = *(const s16x8*)(xs + (((unsigned)(tk << 8) + koff) ^ (unsigned)((tk & 7) << 4)));
        }
      }
      LBAR();

      // ---- 5 pair-intervals: produce chunks {2i, 2i+1}
#pragma unroll
      for (int i = 0; i <= 4; ++i) {
        if (i < 4) {
#pragma unroll
          for (int q = 0; q < 2; ++q) {
            const int cc = 2 * i + q;
            const int hrow = (cc << 6) + (hr << 4) + l15;
            const unsigned hswz = (unsigned)((hrow & 7) << 4);
            s16x8 a[4];
#pragma unroll
            for (int ks = 0; ks < 4; ++ks) {
              unsigned koff = (unsigned)((ks << 6) + (lg << 4));
              a[ks] = *(const s16x8*)(w1s + (((unsigned)(hrow << 8) + koff) ^ hswz));
            }
            f32x4 acc1[2];
            acc1[0] = (f32x4){0.f, 0.f, 0.f, 0.f};
            acc1[1] = (f32x4){0.f, 0.f, 0.f, 0.f};
            __builtin_amdgcn_s_setprio(1);
#pragma unroll
            for (int j = 0; j < 2; ++j)
#pragma unroll
              for (int ks = 0; ks < 4; ++ks)
                acc1[j] = __builtin_amdgcn_mfma_f32_16x16x32_bf16(a[ks], xb[j][ks], acc1[j], 0, 0, 0);
            __builtin_amdgcn_s_setprio(0);

            char* const hw = hbuf[cc & 3];
#pragma unroll
            for (int j = 0; j < 2; ++j) {
              int tk = tq0 + (j << 4) + l15;
              u16x4 qv;
#pragma unroll
              for (int r = 0; r < 4; ++r)
                qv[r] = f2bf(fmaxf(acc1[j][r] + bias[cc][r], 0.f));
              *(u16x4*)(hw + (((unsigned)(tk << 7) + hl2) ^ (unsigned)((tk & 7) << 4))) = qv;
            }
          }
        }
        if (i == 2 && t < 15) {
          const float* xn = xblk + (((size_t)t + 1) << 13);
          xv[0] = *(const f32x4*)(xn + (tid << 3));
          xv[1] = *(const f32x4*)(xn + (tid << 3) + 4);
        }
        LBAR();
      }
    }
  } else {
    // ================= CONSUMER: GEMM2 + store =================
    const int cw = wid - 8;
    const int dlane = (cw << 4) + l15;
    char* const hbuf[4] = {hb0, hb1, hb2, hb3};

    // w2 fragments: wave owns d-slice [cw*16, cw*16+16), all 512 h (64 VGPR)
    s16x8 w2f[8][2];
#pragma unroll
    for (int c = 0; c < 8; ++c)
#pragma unroll
      for (int ks = 0; ks < 2; ++ks)
        w2f[c][ks] = *(const s16x8*)(w2g + ((size_t)dlane << 9) + (c << 6) + (ks << 5) + (lg << 3));

    const float b2v   = b2[(e << 7) + dlane];
    const float scale = expf(fminf(temp[0], CLAMP_MAXV));

#pragma unroll 1
    for (int t = 0; t < 16; ++t) {
      // write xs (same mapping as producers)
      u16x8 p;
#pragma unroll
      for (int i = 0; i < 8; ++i) p[i] = f2bf(xv[i >> 2][i & 3]);
      *(u16x8*)(xs + xaddr) = p;
      LBAR();
      // (producers hoist here)
      LBAR();

      f32x4 acc2[4];
#pragma unroll
      for (int i = 0; i < 4; ++i) acc2[i] = (f32x4){0.f, 0.f, 0.f, 0.f};

      // ---- 5 pair-intervals: consume chunks {2i-2, 2i-1}
#pragma unroll
      for (int i = 0; i <= 4; ++i) {
        if (i >= 1) {
#pragma unroll
          for (int q = 0; q < 2; ++q) {
            const int cc = 2 * (i - 1) + q;
            char* const hrd = hbuf[cc & 3];
            s16x8 ha[4][2];
#pragma unroll
            for (int ii = 0; ii < 4; ++ii) {
              int tk = (ii << 4) + l15;
              unsigned tswz = (unsigned)((tk & 7) << 4);
#pragma unroll
              for (int ks = 0; ks < 2; ++ks) {
                unsigned koff = (unsigned)((ks << 6) + (lg << 4));
                ha[ii][ks] = *(const s16x8*)(hrd + (((unsigned)(tk << 7) + koff) ^ tswz));
              }
            }
            __builtin_amdgcn_s_setprio(1);
#pragma unroll
            for (int ii = 0; ii < 4; ++ii)
#pragma unroll
              for (int ks = 0; ks < 2; ++ks)
                acc2[ii] = __builtin_amdgcn_mfma_f32_16x16x32_bf16(ha[ii][ks], w2f[cc][ks], acc2[ii], 0, 0, 0);
            __builtin_amdgcn_s_setprio(0);
          }
        }
        if (i == 2 && t < 15) {
          const float* xn = xblk + (((size_t)t + 1) << 13);
          xv[0] = *(const f32x4*)(xn + (tid << 3));
          xv[1] = *(const f32x4*)(xn + (tid << 3) + 4);
        }
        LBAR();
      }

      // store tile t: wave covers all 64 tok x its 16 d
      float* og = oblk + ((size_t)t << 13);
#pragma unroll
      for (int i = 0; i < 4; ++i) {
#pragma unroll
        for (int r = 0; r < 4; ++r) {
          int tk = (i << 4) + (lg << 2) + r;
          og[((size_t)tk << 7) + dlane] = (acc2[i][r] + b2v) * scale;
        }
      }
    }
  }
}

// ---- fallback (only if ws_size is tiny): naive but correct
__global__ void moe_naive(const float* __restrict__ x, const float* __restrict__ W1,
                          const float* __restrict__ b1, const float* __restrict__ W2,
                          const float* __restrict__ b2, const float* __restrict__ temp,
                          float* __restrict__ out) {
  __shared__ float xr[128];
  __shared__ float hrow[512];
  int t = blockIdx.x;
  int e = t >> 16;
  int tx = threadIdx.x;
  xr[tx] = x[((size_t)t << 7) + tx];
  __syncthreads();
  const float* w1e = W1 + ((size_t)e << 16);
  for (int h = tx; h < 512; h += 128) {
    float s = b1[(e << 9) + h];
    for (int d = 0; d < 128; ++d) s += xr[d] * w1e[(size_t)d * 512 + h];
    hrow[h] = fmaxf(s, 0.f);
  }
  __syncthreads();
  const float* w2e = W2 + ((size_t)e << 16);
  float s = b2[(e << 7) + tx];
  for (int h = 0; h < 512; ++h) s += hrow[h] * w2e[(size_t)h * 128 + tx];
  out[((size_t)t << 7) + tx] = s * expf(fminf(temp[0], CLAMP_MAXV));
}

extern "C" void kernel_launch(void* const* d_in, const int* in_sizes, int n_in,
                              void* d_out, int out_size, void* d_ws, size_t ws_size,
                              hipStream_t stream) {
  const float* x    = (const float*)d_in[0];
  const float* W1   = (const float*)d_in[1];
  const float* b1   = (const float*)d_in[2];
  const float* W2   = (const float*)d_in[3];
  const float* b2   = (const float*)d_in[4];
  const float* temp = (const float*)d_in[5];
  float* out = (float*)d_out;

  const size_t WS_NEEDED = 2u * 524288u * sizeof(unsigned short);  // 2 MB
  if (ws_size >= WS_NEEDED) {
    unsigned short* w1t = (unsigned short*)d_ws;
    unsigned short* w2t = w1t + 524288;
    conv_w<<<512, 256, 0, stream>>>(W1, W2, w1t, w2t);
    moe_fused<<<512, 1024, 0, stream>>>(x, b1, b2, temp, w1t, w2t, out);
  } else {
    moe_naive<<<524288, 128, 0, stream>>>(x, W1, b1, W2, b2, temp, out);
  }
}

// Round 9
// 215.518 us; speedup vs baseline: 1.6334x; 1.6334x over previous
//
#include <hip/hip_runtime.h>

// MoE fused forward: out = (relu(x@W1[e]+b1[e])@W2[e]+b2[e]) * exp(min(T, log100))
// N=524288, D=128, H=512, E=8, contiguous expert chunks.
// R9: R6's producer/consumer wave specialization + R8's pair-chunk 4-buf ring,
// implemented REGISTER-NEUTRAL vs R6 (R8 spilled: FETCH +545MB): bias via
// per-chunk global dwordx4 (L1-hot, transient), ring addressing by pointer
// arithmetic (no array), consumer ha reads inline (no batching). Post-hoist
// barrier removed (hoist reads drain at interval-0 lgkmcnt(0); first write to
// the xs-aliased bufs {2,3} is 1 barrier later). Barriers/tile 11 -> 6.
// LDS = w1s 128K + ring 4x8K = 160 KiB exactly (xs aliases ring bufs 2,3).

#define CLAMP_MAXV 4.605170185988091f

typedef __attribute__((ext_vector_type(8))) short s16x8;
typedef __attribute__((ext_vector_type(4))) float f32x4;
typedef __attribute__((ext_vector_type(4))) unsigned short u16x4;
typedef __attribute__((ext_vector_type(8))) unsigned short u16x8;

static __device__ __forceinline__ unsigned short f2bf(float f) {
  union { float f; unsigned int u; } v; v.f = f;
  unsigned int r = v.u + 0x7FFFu + ((v.u >> 16) & 1u);  // RNE
  return (unsigned short)(r >> 16);
}

static __device__ __forceinline__ void gll16(const void* src, void* dst) {
  __builtin_amdgcn_global_load_lds((const __attribute__((address_space(1))) void*)src,
                                   (__attribute__((address_space(3))) void*)dst, 16, 0, 0);
}

// LDS-only barrier: own-wave lgkm drain + s_barrier (vmcnt NOT drained; in-flight
// VMEM are reg loads, waited by compiler before use).
#define LBAR() do { \
  asm volatile("s_waitcnt lgkmcnt(0)" ::: "memory"); \
  __builtin_amdgcn_s_barrier(); \
  __builtin_amdgcn_sched_barrier(0); \
} while (0)

// ---- pre-kernel: W1[e][d][h] -> w1t[e][h][d] bf16 ; W2[e][h][d] -> w2t[e][d][h] bf16
__global__ void conv_w(const float* __restrict__ W1, const float* __restrict__ W2,
                       unsigned short* __restrict__ w1t, unsigned short* __restrict__ w2t) {
  int idx = blockIdx.x * 256 + threadIdx.x;  // 131072 total
  if (idx < 65536) {
    int h  = idx & 511;
    int d0 = ((idx >> 9) & 15) << 3;
    int e  = idx >> 13;
    const float* src = W1 + ((size_t)e << 16);
    u16x8 v;
#pragma unroll
    for (int j = 0; j < 8; ++j) v[j] = f2bf(src[(size_t)(d0 + j) * 512 + h]);
    *(u16x8*)(w1t + ((((size_t)e << 9) + h) << 7) + d0) = v;
  } else {
    int i2 = idx - 65536;
    int d  = i2 & 127;
    int h0 = ((i2 >> 7) & 63) << 3;
    int e  = i2 >> 13;
    const float* src = W2 + ((size_t)e << 16);
    u16x8 v;
#pragma unroll
    for (int j = 0; j < 8; ++j) v[j] = f2bf(src[(size_t)(h0 + j) * 128 + d]);
    *(u16x8*)(w2t + ((((size_t)e << 7) + d) << 9) + h0) = v;
  }
}

// ---- fused MoE kernel (wave-specialized, pair-chunk ring, register-neutral)
__global__ __launch_bounds__(1024, 4) void moe_fused(
    const float* __restrict__ x,
    const float* __restrict__ b1,
    const float* __restrict__ b2,
    const float* __restrict__ temp,
    const unsigned short* __restrict__ w1t,
    const unsigned short* __restrict__ w2t,
    float* __restrict__ out)
{
  __shared__ __align__(16) char smem[163840];
  char* const w1s  = smem;             // 128 KB [512 h][128 d] bf16, swz ^((h&7)<<4)
  char* const ring = smem + 131072;    // 4 x 8 KB [64 tok][64 h] bf16, swz ^((tok&7)<<4)
  char* const xs   = smem + 147456;    // 16 KB [64 tok][128 d] bf16 (aliases ring bufs 2,3)

  const int tid  = threadIdx.x;
  const int lane = tid & 63;
  const int wid  = tid >> 6;          // 0..15
  const int l15  = lane & 15;
  const int lg   = lane >> 4;
  const int blk  = blockIdx.x;
  const int e    = blk >> 6;          // 64 blocks per expert
  const size_t tok0 = (size_t)blk << 10;   // 1024 tokens per block

  const unsigned short* w1g = w1t + ((size_t)e << 16);
  const unsigned short* w2g = w2t + ((size_t)e << 16);
  const float* xblk = x + (tok0 << 7);
  float* const oblk = out + (tok0 << 7);

  // ---- prologue: stage w1 (128 KB) once per block, source pre-swizzled
#pragma unroll
  for (int k = 0; k < 8; ++k) {
    int s = tid + (k << 10);          // 0..8191 slots of 16 B
    int h = s >> 4, sr = s & 15;
    gll16(w1g + ((size_t)h << 7) + ((sr ^ (h & 7)) << 3), w1s + (s << 4));
  }

  // x tile 0 into regs (each thread owns 8 floats)
  f32x4 xv[2];
  xv[0] = *(const f32x4*)(xblk + (tid << 3));
  xv[1] = *(const f32x4*)(xblk + (tid << 3) + 4);

  __syncthreads();  // full drain: w1s landed

  // xs-write address: tok = tid>>4, col = (tid&15)*8
  const int xtok = tid >> 4;
  const unsigned xaddr = (unsigned)((xtok << 8) + ((tid & 15) << 4)) ^ (unsigned)((xtok & 7) << 4);

  if (wid < 8) {
    // ================= PRODUCER: GEMM1 =================
    const int hr  = wid & 3;
    const int tq0 = (wid >> 2) << 5;
    const unsigned hl2 = (unsigned)(((hr << 4) + (lg << 2)) << 1);
    const float* b1e = b1 + (e << 9);

#pragma unroll 1
    for (int t = 0; t < 16; ++t) {
      // write xs
      u16x8 p;
#pragma unroll
      for (int i = 0; i < 8; ++i) p[i] = f2bf(xv[i >> 2][i & 3]);
      *(u16x8*)(xs + xaddr) = p;
      LBAR();   // (A) xs visible

      // hoist x fragments (reads drain at the interval-0 LBAR; first write to
      // the xs-aliased bufs {2,3} is interval 1 -- one barrier later)
      s16x8 xb[2][4];
#pragma unroll
      for (int j = 0; j < 2; ++j) {
        int tk = tq0 + (j << 4) + l15;
#pragma unroll
        for (int ks = 0; ks < 4; ++ks) {
          unsigned koff = (unsigned)((ks << 6) + (lg << 4));
          xb[j][ks] = *(const s16x8*)(xs + (((unsigned)(tk << 8) + koff) ^ (unsigned)((tk & 7) << 4)));
        }
      }

      // ---- 5 pair-intervals: produce chunks {2i, 2i+1} -> ring bufs {2i&3, (2i+1)&3}
#pragma unroll
      for (int i = 0; i <= 4; ++i) {
        if (i < 4) {
#pragma unroll
          for (int q = 0; q < 2; ++q) {
            const int cc = 2 * i + q;
            const int hrow = (cc << 6) + (hr << 4) + l15;
            const unsigned hswz = (unsigned)((hrow & 7) << 4);
            s16x8 a[4];
#pragma unroll
            for (int ks = 0; ks < 4; ++ks) {
              unsigned koff = (unsigned)((ks << 6) + (lg << 4));
              a[ks] = *(const s16x8*)(w1s + (((unsigned)(hrow << 8) + koff) ^ hswz));
            }
            f32x4 bias = *(const f32x4*)(b1e + (cc << 6) + (hr << 4) + (lg << 2));
            f32x4 acc1[2];
            acc1[0] = (f32x4){0.f, 0.f, 0.f, 0.f};
            acc1[1] = (f32x4){0.f, 0.f, 0.f, 0.f};
            __builtin_amdgcn_s_setprio(1);
#pragma unroll
            for (int j = 0; j < 2; ++j)
#pragma unroll
              for (int ks = 0; ks < 4; ++ks)
                acc1[j] = __builtin_amdgcn_mfma_f32_16x16x32_bf16(a[ks], xb[j][ks], acc1[j], 0, 0, 0);
            __builtin_amdgcn_s_setprio(0);

            char* const hw = ring + ((unsigned)(cc & 3) << 13);
#pragma unroll
            for (int j = 0; j < 2; ++j) {
              int tk = tq0 + (j << 4) + l15;
              u16x4 qv;
#pragma unroll
              for (int r = 0; r < 4; ++r)
                qv[r] = f2bf(fmaxf(acc1[j][r] + bias[r], 0.f));
              *(u16x4*)(hw + (((unsigned)(tk << 7) + hl2) ^ (unsigned)((tk & 7) << 4))) = qv;
            }
          }
        }
        if (i == 2 && t < 15) {
          const float* xn = xblk + (((size_t)t + 1) << 13);
          xv[0] = *(const f32x4*)(xn + (tid << 3));
          xv[1] = *(const f32x4*)(xn + (tid << 3) + 4);
        }
        LBAR();
      }
    }
  } else {
    // ================= CONSUMER: GEMM2 + store =================
    const int cw = wid - 8;
    const int dlane = (cw << 4) + l15;

    // w2 fragments: wave owns d-slice [cw*16, cw*16+16), all 512 h (64 VGPR)
    s16x8 w2f[8][2];
#pragma unroll
    for (int c = 0; c < 8; ++c)
#pragma unroll
      for (int ks = 0; ks < 2; ++ks)
        w2f[c][ks] = *(const s16x8*)(w2g + ((size_t)dlane << 9) + (c << 6) + (ks << 5) + (lg << 3));

    const float b2v   = b2[(e << 7) + dlane];
    const float scale = expf(fminf(temp[0], CLAMP_MAXV));

#pragma unroll 1
    for (int t = 0; t < 16; ++t) {
      // write xs (same mapping as producers)
      u16x8 p;
#pragma unroll
      for (int i = 0; i < 8; ++i) p[i] = f2bf(xv[i >> 2][i & 3]);
      *(u16x8*)(xs + xaddr) = p;
      LBAR();   // (A)

      f32x4 acc2[4];
#pragma unroll
      for (int i = 0; i < 4; ++i) acc2[i] = (f32x4){0.f, 0.f, 0.f, 0.f};

      // ---- 5 pair-intervals: consume chunks {2i-2, 2i-1}
#pragma unroll
      for (int i = 0; i <= 4; ++i) {
        if (i >= 1) {
          __builtin_amdgcn_s_setprio(1);
#pragma unroll
          for (int q = 0; q < 2; ++q) {
            const int cc = 2 * (i - 1) + q;
            char* const hrd = ring + ((unsigned)(cc & 3) << 13);
#pragma unroll
            for (int ii = 0; ii < 4; ++ii) {
              int tk = (ii << 4) + l15;
              unsigned tswz = (unsigned)((tk & 7) << 4);
#pragma unroll
              for (int ks = 0; ks < 2; ++ks) {
                unsigned koff = (unsigned)((ks << 6) + (lg << 4));
                s16x8 ha = *(const s16x8*)(hrd + (((unsigned)(tk << 7) + koff) ^ tswz));
                acc2[ii] = __builtin_amdgcn_mfma_f32_16x16x32_bf16(ha, w2f[cc][ks], acc2[ii], 0, 0, 0);
              }
            }
          }
          __builtin_amdgcn_s_setprio(0);
        }
        if (i == 2 && t < 15) {
          const float* xn = xblk + (((size_t)t + 1) << 13);
          xv[0] = *(const f32x4*)(xn + (tid << 3));
          xv[1] = *(const f32x4*)(xn + (tid << 3) + 4);
        }
        LBAR();
      }

      // store tile t: wave covers all 64 tok x its 16 d
      float* og = oblk + ((size_t)t << 13);
#pragma unroll
      for (int i = 0; i < 4; ++i) {
#pragma unroll
        for (int r = 0; r < 4; ++r) {
          int tk = (i << 4) + (lg << 2) + r;
          og[((size_t)tk << 7) + dlane] = (acc2[i][r] + b2v) * scale;
        }
      }
    }
  }
}

// ---- fallback (only if ws_size is tiny): naive but correct
__global__ void moe_naive(const float* __restrict__ x, const float* __restrict__ W1,
                          const float* __restrict__ b1, const float* __restrict__ W2,
                          const float* __restrict__ b2, const float* __restrict__ temp,
                          float* __restrict__ out) {
  __shared__ float xr[128];
  __shared__ float hrow[512];
  int t = blockIdx.x;
  int e = t >> 16;
  int tx = threadIdx.x;
  xr[tx] = x[((size_t)t << 7) + tx];
  __syncthreads();
  const float* w1e = W1 + ((size_t)e << 16);
  for (int h = tx; h < 512; h += 128) {
    float s = b1[(e << 9) + h];
    for (int d = 0; d < 128; ++d) s += xr[d] * w1e[(size_t)d * 512 + h];
    hrow[h] = fmaxf(s, 0.f);
  }
  __syncthreads();
  const float* w2e = W2 + ((size_t)e << 16);
  float s = b2[(e << 7) + tx];
  for (int h = 0; h < 512; ++h) s += hrow[h] * w2e[(size_t)h * 128 + tx];
  out[((size_t)t << 7) + tx] = s * expf(fminf(temp[0], CLAMP_MAXV));
}

extern "C" void kernel_launch(void* const* d_in, const int* in_sizes, int n_in,
                              void* d_out, int out_size, void* d_ws, size_t ws_size,
                              hipStream_t stream) {
  const float* x    = (const float*)d_in[0];
  const float* W1   = (const float*)d_in[1];
  const float* b1   = (const float*)d_in[2];
  const float* W2   = (const float*)d_in[3];
  const float* b2   = (const float*)d_in[4];
  const float* temp = (const float*)d_in[5];
  float* out = (float*)d_out;

  const size_t WS_NEEDED = 2u * 524288u * sizeof(unsigned short);  // 2 MB
  if (ws_size >= WS_NEEDED) {
    unsigned short* w1t = (unsigned short*)d_ws;
    unsigned short* w2t = w1t + 524288;
    conv_w<<<512, 256, 0, stream>>>(W1, W2, w1t, w2t);
    moe_fused<<<512, 1024, 0, stream>>>(x, b1, b2, temp, w1t, w2t, out);
  } else {
    moe_naive<<<524288, 128, 0, stream>>>(x, W1, b1, W2, b2, temp, out);
  }
}

// Round 10
// 178.578 us; speedup vs baseline: 1.9712x; 1.2069x over previous
//
#include <hip/hip_runtime.h>

// MoE fused forward: out = (relu(x@W1[e]+b1[e])@W2[e]+b2[e]) * exp(min(T, log100))
// N=524288, D=128, H=512, E=8, contiguous expert chunks.
// R10: R6 base (producer/consumer wave specialization, 512 blocks x 1024 thr,
// best 178us) + three register-counted LDS-byte reductions:
//  (1) xs de-aliased (own 16KB) -> post-hoist barrier provably removable
//      (hoist reads vs next xs write are 10 barriers apart). 11 -> 10 barriers.
//  (2) w1 chunks 0-1 in producer regs (w1r[2][4]=32 VGPR, loaded from L2 once);
//      w1s shrinks to 96KB (h=128..511); per-tile a-reads 256->192KB.
//  (3) no setprio (R8/R9's setprio-around-ds_read regions is a regression suspect).
// Register audit: producer ~110, consumer ~102 (<128 for 4 waves/EU).

#define CLAMP_MAXV 4.605170185988091f

typedef __attribute__((ext_vector_type(8))) short s16x8;
typedef __attribute__((ext_vector_type(4))) float f32x4;
typedef __attribute__((ext_vector_type(4))) unsigned short u16x4;
typedef __attribute__((ext_vector_type(8))) unsigned short u16x8;

static __device__ __forceinline__ unsigned short f2bf(float f) {
  union { float f; unsigned int u; } v; v.f = f;
  unsigned int r = v.u + 0x7FFFu + ((v.u >> 16) & 1u);  // RNE
  return (unsigned short)(r >> 16);
}

static __device__ __forceinline__ void gll16(const void* src, void* dst) {
  __builtin_amdgcn_global_load_lds((const __attribute__((address_space(1))) void*)src,
                                   (__attribute__((address_space(3))) void*)dst, 16, 0, 0);
}

// LDS-only barrier: own-wave lgkm drain + s_barrier (vmcnt NOT drained; in-flight
// VMEM are reg loads, waited by compiler before use).
#define LBAR() do { \
  asm volatile("s_waitcnt lgkmcnt(0)" ::: "memory"); \
  __builtin_amdgcn_s_barrier(); \
  __builtin_amdgcn_sched_barrier(0); \
} while (0)

// ---- pre-kernel: W1[e][d][h] -> w1t[e][h][d] bf16 ; W2[e][h][d] -> w2t[e][d][h] bf16
__global__ void conv_w(const float* __restrict__ W1, const float* __restrict__ W2,
                       unsigned short* __restrict__ w1t, unsigned short* __restrict__ w2t) {
  int idx = blockIdx.x * 256 + threadIdx.x;  // 131072 total
  if (idx < 65536) {
    int h  = idx & 511;
    int d0 = ((idx >> 9) & 15) << 3;
    int e  = idx >> 13;
    const float* src = W1 + ((size_t)e << 16);
    u16x8 v;
#pragma unroll
    for (int j = 0; j < 8; ++j) v[j] = f2bf(src[(size_t)(d0 + j) * 512 + h]);
    *(u16x8*)(w1t + ((((size_t)e << 9) + h) << 7) + d0) = v;
  } else {
    int i2 = idx - 65536;
    int d  = i2 & 127;
    int h0 = ((i2 >> 7) & 63) << 3;
    int e  = i2 >> 13;
    const float* src = W2 + ((size_t)e << 16);
    u16x8 v;
#pragma unroll
    for (int j = 0; j < 8; ++j) v[j] = f2bf(src[(size_t)(h0 + j) * 128 + d]);
    *(u16x8*)(w2t + ((((size_t)e << 7) + d) << 9) + h0) = v;
  }
}

// ---- fused MoE kernel (wave-specialized)
__global__ __launch_bounds__(1024, 4) void moe_fused(
    const float* __restrict__ x,
    const float* __restrict__ b1,
    const float* __restrict__ b2,
    const float* __restrict__ temp,
    const unsigned short* __restrict__ w1t,
    const unsigned short* __restrict__ w2t,
    float* __restrict__ out)
{
  __shared__ __align__(16) char smem[133120];
  char* const w1s  = smem;             // 96 KB [h=128..511][128 d] bf16, swz ^((h&7)<<4)
  char* const hsb0 = smem + 98304;     //  8 KB [64 tok][64 h] bf16, swz ^((tok&7)<<4)
  char* const hsb1 = smem + 106496;    //  8 KB
  char* const xs   = smem + 114688;    // 16 KB [64 tok][128 d] bf16 (NOT aliased)
  float* const b1s = (float*)(smem + 131072);  // 2 KB

  const int tid  = threadIdx.x;
  const int lane = tid & 63;
  const int wid  = tid >> 6;          // 0..15
  const int l15  = lane & 15;
  const int lg   = lane >> 4;
  const int blk  = blockIdx.x;
  const int e    = blk >> 6;          // 64 blocks per expert
  const size_t tok0 = (size_t)blk << 10;   // 1024 tokens per block

  const unsigned short* w1g = w1t + ((size_t)e << 16);
  const unsigned short* w2g = w2t + ((size_t)e << 16);
  const float* xblk = x + (tok0 << 7);
  float* const oblk = out + (tok0 << 7);

  // ---- prologue: stage w1 rows 128..511 (96 KB) once, source pre-swizzled
#pragma unroll
  for (int k = 0; k < 6; ++k) {
    int s = tid + (k << 10);          // 0..6143 slots of 16 B
    int hl = s >> 4, sr = s & 15;     // LDS row 0..383 == global h-128
    gll16(w1g + ((size_t)(hl + 128) << 7) + ((sr ^ (hl & 7)) << 3), w1s + (s << 4));
  }

  if (tid < 512) b1s[tid] = b1[(e << 9) + tid];

  // x tile 0 into regs (each thread owns 8 floats)
  f32x4 xv[2];
  xv[0] = *(const f32x4*)(xblk + (tid << 3));
  xv[1] = *(const f32x4*)(xblk + (tid << 3) + 4);

  // xs-write address: tok = tid>>4, col = (tid&15)*8
  const int xtok = tid >> 4;
  const unsigned xaddr = (unsigned)((xtok << 8) + ((tid & 15) << 4)) ^ (unsigned)((xtok & 7) << 4);

  if (wid < 8) {
    // ================= PRODUCER: GEMM1 =================
    const int hr  = wid & 3;
    const int tq0 = (wid >> 2) << 5;
    const unsigned hl2 = (unsigned)(((hr << 4) + (lg << 2)) << 1);

    // w1 chunks 0-1 fragments in regs (loaded from global/L2, plain [h][d] layout)
    s16x8 w1r[2][4];
#pragma unroll
    for (int c = 0; c < 2; ++c) {
      const int hrow = (c << 6) + (hr << 4) + l15;
#pragma unroll
      for (int ks = 0; ks < 4; ++ks)
        w1r[c][ks] = *(const s16x8*)(w1g + ((size_t)hrow << 7) + (ks << 5) + (lg << 3));
    }

    __syncthreads();  // full drain: w1s + b1s landed (also covers w1r/xv issue)

#pragma unroll 1
    for (int t = 0; t < 16; ++t) {
      // write xs
      u16x8 p;
#pragma unroll
      for (int i = 0; i < 8; ++i) p[i] = f2bf(xv[i >> 2][i & 3]);
      *(u16x8*)(xs + xaddr) = p;
      LBAR();   // xs visible

      // hoist x fragments; no barrier needed after (xs not rewritten for 10 barriers)
      s16x8 xb[2][4];
#pragma unroll
      for (int j = 0; j < 2; ++j) {
        int tk = tq0 + (j << 4) + l15;
#pragma unroll
        for (int ks = 0; ks < 4; ++ks) {
          unsigned koff = (unsigned)((ks << 6) + (lg << 4));
          xb[j][ks] = *(const s16x8*)(xs + (((unsigned)(tk << 8) + koff) ^ (unsigned)((tk & 7) << 4)));
        }
      }

#pragma unroll
      for (int c = 0; c <= 8; ++c) {
        if (c < 8) {
          f32x4 bias = *(const f32x4*)(b1s + (c << 6) + (hr << 4) + (lg << 2));
          f32x4 acc1[2];
          acc1[0] = (f32x4){0.f, 0.f, 0.f, 0.f};
          acc1[1] = (f32x4){0.f, 0.f, 0.f, 0.f};
          if (c < 2) {
#pragma unroll
            for (int j = 0; j < 2; ++j)
#pragma unroll
              for (int ks = 0; ks < 4; ++ks)
                acc1[j] = __builtin_amdgcn_mfma_f32_16x16x32_bf16(w1r[c][ks], xb[j][ks], acc1[j], 0, 0, 0);
          } else {
            const int hrow = (c << 6) + (hr << 4) + l15;   // global h (>=128)
            const unsigned hswz = (unsigned)((hrow & 7) << 4);
            s16x8 a[4];
#pragma unroll
            for (int ks = 0; ks < 4; ++ks) {
              unsigned koff = (unsigned)((ks << 6) + (lg << 4));
              a[ks] = *(const s16x8*)(w1s + (((unsigned)((hrow - 128) << 8) + koff) ^ hswz));
            }
#pragma unroll
            for (int j = 0; j < 2; ++j)
#pragma unroll
              for (int ks = 0; ks < 4; ++ks)
                acc1[j] = __builtin_amdgcn_mfma_f32_16x16x32_bf16(a[ks], xb[j][ks], acc1[j], 0, 0, 0);
          }

          char* const hw = (c & 1) ? hsb1 : hsb0;
#pragma unroll
          for (int j = 0; j < 2; ++j) {
            int tk = tq0 + (j << 4) + l15;
            u16x4 qv;
#pragma unroll
            for (int r = 0; r < 4; ++r)
              qv[r] = f2bf(fmaxf(acc1[j][r] + bias[r], 0.f));
            *(u16x4*)(hw + (((unsigned)(tk << 7) + hl2) ^ (unsigned)((tk & 7) << 4))) = qv;
          }
        }
        if (c == 4 && t < 15) {
          const float* xn = xblk + (((size_t)t + 1) << 13);
          xv[0] = *(const f32x4*)(xn + (tid << 3));
          xv[1] = *(const f32x4*)(xn + (tid << 3) + 4);
        }
        LBAR();
      }
    }
  } else {
    // ================= CONSUMER: GEMM2 + store =================
    const int cw = wid - 8;
    const int dlane = (cw << 4) + l15;

    // w2 fragments: wave owns d-slice [cw*16, cw*16+16), all 512 h (64 VGPR)
    s16x8 w2f[8][2];
#pragma unroll
    for (int c = 0; c < 8; ++c)
#pragma unroll
      for (int ks = 0; ks < 2; ++ks)
        w2f[c][ks] = *(const s16x8*)(w2g + ((size_t)dlane << 9) + (c << 6) + (ks << 5) + (lg << 3));

    const float b2v   = b2[(e << 7) + dlane];
    const float scale = expf(fminf(temp[0], CLAMP_MAXV));

    __syncthreads();  // full drain: matches producer barrier

#pragma unroll 1
    for (int t = 0; t < 16; ++t) {
      // write xs (same mapping as producers)
      u16x8 p;
#pragma unroll
      for (int i = 0; i < 8; ++i) p[i] = f2bf(xv[i >> 2][i & 3]);
      *(u16x8*)(xs + xaddr) = p;
      LBAR();

      f32x4 acc2[4];
#pragma unroll
      for (int i = 0; i < 4; ++i) acc2[i] = (f32x4){0.f, 0.f, 0.f, 0.f};

#pragma unroll
      for (int c = 0; c <= 8; ++c) {
        if (c >= 1) {
          const int cc = c - 1;
          char* const hrd = (cc & 1) ? hsb1 : hsb0;
#pragma unroll
          for (int ii = 0; ii < 4; ++ii) {
            int tk = (ii << 4) + l15;
            unsigned tswz = (unsigned)((tk & 7) << 4);
#pragma unroll
            for (int ks = 0; ks < 2; ++ks) {
              unsigned koff = (unsigned)((ks << 6) + (lg << 4));
              s16x8 ha = *(const s16x8*)(hrd + (((unsigned)(tk << 7) + koff) ^ tswz));
              acc2[ii] = __builtin_amdgcn_mfma_f32_16x16x32_bf16(ha, w2f[cc][ks], acc2[ii], 0, 0, 0);
            }
          }
        }
        if (c == 4 && t < 15) {
          const float* xn = xblk + (((size_t)t + 1) << 13);
          xv[0] = *(const f32x4*)(xn + (tid << 3));
          xv[1] = *(const f32x4*)(xn + (tid << 3) + 4);
        }
        LBAR();
      }

      // store tile t: wave covers all 64 tok x its 16 d
      float* og = oblk + ((size_t)t << 13);
#pragma unroll
      for (int i = 0; i < 4; ++i) {
#pragma unroll
        for (int r = 0; r < 4; ++r) {
          int tk = (i << 4) + (lg << 2) + r;
          og[((size_t)tk << 7) + dlane] = (acc2[i][r] + b2v) * scale;
        }
      }
    }
  }
}

// ---- fallback (only if ws_size is tiny): naive but correct
__global__ void moe_naive(const float* __restrict__ x, const float* __restrict__ W1,
                          const float* __restrict__ b1, const float* __restrict__ W2,
                          const float* __restrict__ b2, const float* __restrict__ temp,
                          float* __restrict__ out) {
  __shared__ float xr[128];
  __shared__ float hrow[512];
  int t = blockIdx.x;
  int e = t >> 16;
  int tx = threadIdx.x;
  xr[tx] = x[((size_t)t << 7) + tx];
  __syncthreads();
  const float* w1e = W1 + ((size_t)e << 16);
  for (int h = tx; h < 512; h += 128) {
    float s = b1[(e << 9) + h];
    for (int d = 0; d < 128; ++d) s += xr[d] * w1e[(size_t)d * 512 + h];
    hrow[h] = fmaxf(s, 0.f);
  }
  __syncthreads();
  const float* w2e = W2 + ((size_t)e << 16);
  float s = b2[(e << 7) + tx];
  for (int h = 0; h < 512; ++h) s += hrow[h] * w2e[(size_t)h * 128 + tx];
  out[((size_t)t << 7) + tx] = s * expf(fminf(temp[0], CLAMP_MAXV));
}

extern "C" void kernel_launch(void* const* d_in, const int* in_sizes, int n_in,
                              void* d_out, int out_size, void* d_ws, size_t ws_size,
                              hipStream_t stream) {
  const float* x    = (const float*)d_in[0];
  const float* W1   = (const float*)d_in[1];
  const float* b1   = (const float*)d_in[2];
  const float* W2   = (const float*)d_in[3];
  const float* b2   = (const float*)d_in[4];
  const float* temp = (const float*)d_in[5];
  float* out = (float*)d_out;

  const size_t WS_NEEDED = 2u * 524288u * sizeof(unsigned short);  // 2 MB
  if (ws_size >= WS_NEEDED) {
    unsigned short* w1t = (unsigned short*)d_ws;
    unsigned short* w2t = w1t + 524288;
    conv_w<<<512, 256, 0, stream>>>(W1, W2, w1t, w2t);
    moe_fused<<<512, 1024, 0, stream>>>(x, b1, b2, temp, w1t, w2t, out);
  } else {
    moe_naive<<<524288, 128, 0, stream>>>(x, W1, b1, W2, b2, temp, out);
  }
}